// Round 10
// baseline (646.315 us; speedup 1.0000x reference)
//
#include <hip/hip_runtime.h>

typedef unsigned short u16;
typedef unsigned int u32;
typedef __attribute__((ext_vector_type(8))) short bf16x8;
typedef __attribute__((ext_vector_type(4))) float f32x4;

#define N_NODES 524288
#define N_EDGES 4194304
#define N_GRAPH 16384
#define P_BLOCKS 1024          // P1/P2 blocks; 4096 edges each
#define BKTS 512               // coarse buckets = dst>>10
#define DPB 1024               // dsts per bucket
#define CAP 8960               // max edges per bucket
#define TTOT 2825              // transpose blocks: 723200/256
#define LBLK 2048              // linear1 blocks: N/256

__device__ __forceinline__ float bf2f(u16 u){ u32 x=((u32)u)<<16; float f; __builtin_memcpy(&f,&x,4); return f; }
__device__ __forceinline__ float lo2f(u32 u){ u32 x=u<<16; float f; __builtin_memcpy(&f,&x,4); return f; }
__device__ __forceinline__ float hi2f(u32 u){ u32 x=u&0xffff0000u; float f; __builtin_memcpy(&f,&x,4); return f; }
__device__ __forceinline__ u16 f2bf(float f){ u32 x; __builtin_memcpy(&x,&f,4); return (u16)((x + 0x7fffu + ((x>>16)&1u))>>16); }
__device__ __forceinline__ float lrelu(float e){ return e>0.f? e : 0.2f*e; }
__device__ __forceinline__ float gload(const void* p, int i, int is32){
    return is32 ? ((const float*)p)[i] : bf2f(((const u16*)p)[i]);
}
__device__ __forceinline__ u32 fmax_key(float f){ u32 u; __builtin_memcpy(&u,&f,4); return (u>>31)? ~u : (u|0x80000000u); }
__device__ __forceinline__ float key_fmax(u32 k){ u32 u = (k>>31)? (k^0x80000000u) : ~k; float f; __builtin_memcpy(&f,&u,4); return f; }

// accumulate one edge given its 32B row (14 bf16 + fp32 score in q1.w)
__device__ __forceinline__ void edge_acc(uint4 q0, uint4 q1, float adv, float M,
        float* acc, float& den){
    float as_; __builtin_memcpy(&as_, &q1.w, 4);
    float w = __expf(lrelu(as_ + adv) - M); den += w;
    u32 u[7] = {q0.x,q0.y,q0.z,q0.w,q1.x,q1.y,q1.z};
    #pragma unroll
    for (int f=0;f<14;f++){ u32 uu=u[f>>1]; acc[f] += w*((f&1)? hi2f(uu):lo2f(uu)); }
}

// ---------------- 8-deep edge walk, 1 lane per dst, clamped last batch ----------------
__device__ __forceinline__ void walk8(const int* __restrict__ ssrc, const u16* __restrict__ hsrc,
        int beg, int end, float adv, float M, float* acc, float& den){
    for (int j = beg; j < end; j += 8){
        int s8[8];
        #pragma unroll
        for (int k=0;k<8;k++){
            int e = j + k;
            s8[k] = __builtin_nontemporal_load(ssrc + ((e < end) ? e : (end-1)));
        }
        uint4 r0[8], r1[8];
        #pragma unroll
        for (int k=0;k<8;k++){
            const uint4* hp = (const uint4*)(hsrc + (size_t)s8[k]*16);
            r0[k] = hp[0]; r1[k] = hp[1];
        }
        int m = end - j;
        #pragma unroll
        for (int k=0;k<8;k++) if (k < m) edge_acc(r0[k], r1[k], adv, M, acc, den);
    }
}

// ---------------- GEMM block body (bf16 MFMA, 128x128 tile), A may be raw fp32 input ----------------
__device__ __forceinline__ void gemm_block(u16 (*As)[40], u16 (*Bs)[40],
        const void* __restrict__ A, const u16* __restrict__ Wt,
        const void* __restrict__ bias, const void* __restrict__ bnp, void* __restrict__ out,
        int K, int Kp, int Nc, int ostride, int ooff, int do_relu,
        int out32, int araw, int is32, int bm, int bn, int t){
    int af32 = araw && is32;     // A is raw fp32 input -> cast during staging
    int lane = t & 63, wave = t >> 6;
    int mt = (wave & 1) * 64, nt = (wave >> 1) * 64;
    int quad = lane >> 4, fr = lane & 15;

    f32x4 zero = {0.f, 0.f, 0.f, 0.f};
    f32x4 acc[4][4];
    #pragma unroll
    for (int i=0;i<4;i++)
        #pragma unroll
        for (int j=0;j<4;j++) acc[i][j] = zero;

    int srow0 = t >> 2;
    int scol = (t & 3) * 8;

    for (int k0 = 0; k0 < Kp; k0 += 32){
        #pragma unroll
        for (int h2_=0; h2_<2; h2_++){
            int row = srow0 + h2_*64;
            int gk = k0 + scol;
            uint4 av = make_uint4(0,0,0,0);
            if (gk + 8 <= K){
                if (af32){
                    const float* ap = (const float*)A + (size_t)(bm+row)*K + gk;
                    float4 a0 = *(const float4*)ap, a1 = *(const float4*)(ap+4);
                    av.x = (u32)f2bf(a0.x) | ((u32)f2bf(a0.y)<<16);
                    av.y = (u32)f2bf(a0.z) | ((u32)f2bf(a0.w)<<16);
                    av.z = (u32)f2bf(a1.x) | ((u32)f2bf(a1.y)<<16);
                    av.w = (u32)f2bf(a1.z) | ((u32)f2bf(a1.w)<<16);
                } else {
                    av = *(const uint4*)((const u16*)A + (size_t)(bm+row)*K + gk);
                }
            }
            *(uint4*)(&As[row][scol]) = av;
            uint4 bv = make_uint4(0,0,0,0);
            if (bn + row < Nc) bv = *(const uint4*)(Wt + (size_t)(bn+row)*Kp + gk);
            *(uint4*)(&Bs[row][scol]) = bv;
        }
        __syncthreads();
        bf16x8 af[4], bfr[4];
        #pragma unroll
        for (int i=0;i<4;i++) af[i] = *(const bf16x8*)(&As[mt + i*16 + fr][quad*8]);
        #pragma unroll
        for (int j=0;j<4;j++) bfr[j] = *(const bf16x8*)(&Bs[nt + j*16 + fr][quad*8]);
        #pragma unroll
        for (int i=0;i<4;i++)
            #pragma unroll
            for (int j=0;j<4;j++)
                acc[i][j] = __builtin_amdgcn_mfma_f32_16x16x32_bf16(af[i], bfr[j], acc[i][j], 0, 0, 0);
        __syncthreads();
    }

    #pragma unroll
    for (int j=0;j<4;j++){
        int gn = bn + nt + j*16 + fr;
        if (gn >= Nc) continue;
        float bb = gload(bias, gn, is32);
        float scale = 1.f, shift = bb;
        if (bnp){
            float gm_ = gload(bnp, gn, is32), bt = gload(bnp, Nc+gn, is32);
            float mn = gload(bnp, 2*Nc+gn, is32), vr = gload(bnp, 3*Nc+gn, is32);
            scale = gm_ * rsqrtf(vr + 1e-5f);
            shift = (bb - mn)*scale + bt;
        }
        #pragma unroll
        for (int i=0;i<4;i++){
            #pragma unroll
            for (int r=0;r<4;r++){
                int gm = bm + mt + i*16 + quad*4 + r;
                float v = acc[i][j][r]*scale + shift;
                if (do_relu) v = fmaxf(v, 0.f);
                size_t oidx = (size_t)gm*ostride + ooff + gn;
                if (out32) ((float*)out)[oidx] = v;
                else       ((u16*)out)[oidx] = f2bf(v);
            }
        }
    }
}

// ---------------- input dtype detector + prep (va = W2 @ a_s2, vd = W2 @ a_d2) ----------------
__global__ __launch_bounds__(256) void k_detect(const u32* __restrict__ x, int* __restrict__ flag,
        const void* __restrict__ W2, const void* __restrict__ asw, const void* __restrict__ adw,
        float* __restrict__ prep){
    __shared__ int cnt, s32;
    int t = threadIdx.x;
    if (t==0) cnt = 0;
    __syncthreads();
    int c = 0;
    for (int i = t; i < 1024; i += 256){
        u32 e = (x[i] >> 7) & 0xFF;
        if (e >= 110 && e <= 140) c++;
    }
    atomicAdd(&cnt, c);
    __syncthreads();
    if (t==0){ int f = (cnt < 512) ? 1 : 0; *flag = f; s32 = f; }
    __syncthreads();
    int is32 = s32;
    if (t < 28){
        int j = t % 14, which = t / 14;
        const void* av = which ? adw : asw;
        float s = 0.f;
        #pragma unroll
        for (int k=0;k<32;k++) s += gload(W2, j*32+k, is32) * gload(av, k, is32);
        prep[which*14 + j] = s;
    }
}

// ---------------- CSR p1 + 5 weight transposes + GAT layer-1 node linear, one launch ----------------
__global__ __launch_bounds__(256) void k_p1t(const int* __restrict__ dst, u32* __restrict__ tbl_bm,
        const void* __restrict__ Wa, const void* __restrict__ Wb, const void* __restrict__ Wc,
        const void* __restrict__ Wd, const void* __restrict__ We,
        u16* __restrict__ Ta, u16* __restrict__ Tb, u16* __restrict__ Tc,
        u16* __restrict__ Td, u16* __restrict__ Te, const int* __restrict__ flag,
        const void* __restrict__ x, const void* __restrict__ W1,
        const void* __restrict__ asw, const void* __restrict__ adw,
        u16* __restrict__ h1, float* __restrict__ ad1, u32* __restrict__ gkey){
    __shared__ u32 lh[BKTS];
    __shared__ float Wf[196], av14[14], dv14[14];
    __shared__ float red[256];
    int bid = blockIdx.x, t = threadIdx.x;
    if (bid >= P_BLOCKS + TTOT){
        // ---- role 3: linear1 ----
        int is32 = *flag;
        if (t < 196) Wf[t] = gload(W1, t, is32);
        else if (t < 210) av14[t-196] = gload(asw, t-196, is32);
        else if (t < 224) dv14[t-210] = gload(adw, t-210, is32);
        __syncthreads();
        int i = (bid - P_BLOCKS - TTOT)*256 + t;
        float xv[14];
        if (is32){
            const float* xr = (const float*)x + (size_t)i*14;
            #pragma unroll
            for (int k=0;k<14;k++) xv[k] = xr[k];
        } else {
            const u32* xr = (const u32*)((const u16*)x + (size_t)i*14);
            #pragma unroll
            for (int p=0;p<7;p++){ u32 u = xr[p]; xv[2*p]=lo2f(u); xv[2*p+1]=hi2f(u); }
        }
        float h[14];
        #pragma unroll
        for (int j=0;j<14;j++){ float s=0.f;
            #pragma unroll
            for (int k=0;k<14;k++) s += xv[k]*Wf[k*14+j];
            h[j]=s; }
        float a=0.f, d=0.f;
        #pragma unroll
        for (int j=0;j<14;j++){ a += h[j]*av14[j]; d += h[j]*dv14[j]; }
        ad1[i]=d;
        u32 ou[8];
        #pragma unroll
        for (int p=0;p<7;p++) ou[p] = (u32)f2bf(h[2*p]) | ((u32)f2bf(h[2*p+1])<<16);
        __builtin_memcpy(&ou[7], &a, 4);
        uint4* hp = (uint4*)(h1 + (size_t)i*16);
        hp[0] = make_uint4(ou[0],ou[1],ou[2],ou[3]);
        hp[1] = make_uint4(ou[4],ou[5],ou[6],ou[7]);
        red[t] = a; __syncthreads();
        for (int o=128;o;o>>=1){ if (t<o) red[t]=fmaxf(red[t],red[t+o]); __syncthreads(); }
        if (t==0) atomicMax(gkey, fmax_key(red[0]));
        return;
    }
    if (bid >= P_BLOCKS){
        // ---- role 2: weight transpose ----
        int is32 = *flag;
        int loc = (bid - P_BLOCKS)*256 + t;
        const int n1=400*1024, n2=200*416, n3=400*256, n4=200*416, n5=100*448;
        const void* W; u16* T; int K, Kp, Nc;
        if (loc < n1){ W=Wa; T=Ta; K=1024; Kp=1024; Nc=400; }
        else if ((loc-=n1) < n2){ W=Wb; T=Tb; K=400; Kp=416; Nc=200; }
        else if ((loc-=n2) < n3){ W=Wc; T=Tc; K=256; Kp=256; Nc=400; }
        else if ((loc-=n3) < n4){ W=Wd; T=Td; K=400; Kp=416; Nc=200; }
        else if ((loc-=n4) < n5){ W=We; T=Te; K=432; Kp=448; Nc=100; }
        else return;
        int n = loc / Kp, k = loc - n*Kp;
        T[loc] = (k < K) ? f2bf(gload(W, k*Nc + n, is32)) : (u16)0;
        return;
    }
    // ---- role 1: CSR p1 histogram ----
    int blk = bid;
    lh[t] = 0; lh[t+256] = 0;
    __syncthreads();
    int base = blk*4096;
    #pragma unroll
    for (int k=0;k<16;k++){
        int d = __builtin_nontemporal_load(dst + base + k*256 + t) & (N_NODES-1);
        atomicAdd(&lh[d>>10], 1);
    }
    __syncthreads();
    tbl_bm[blk*BKTS + t]       = lh[t];
    tbl_bm[blk*BKTS + t + 256] = lh[t+256];
}

__global__ __launch_bounds__(256) void k_ttbl(const u32* __restrict__ bm, u32* __restrict__ km){
    __shared__ u32 tile[32][33];
    int bx = blockIdx.x, by = blockIdx.y;
    int tx = threadIdx.x & 31, ty = threadIdx.x >> 5;
    #pragma unroll
    for (int r=0;r<32;r+=8)
        tile[ty+r][tx] = bm[(bx*32 + ty + r)*BKTS + by*32 + tx];
    __syncthreads();
    #pragma unroll
    for (int r=0;r<32;r+=8)
        km[(by*32 + ty + r)*P_BLOCKS + bx*32 + tx] = tile[tx][ty+r];
}

__global__ __launch_bounds__(256) void k_scan1(int* __restrict__ data, int* __restrict__ bsums){
    __shared__ int sh[256];
    int b = blockIdx.x, t = threadIdx.x;
    int base = b*1024 + t*4;
    int4 v = *(const int4*)(data + base);
    int s = v.x+v.y+v.z+v.w;
    sh[t] = s; __syncthreads();
    for (int off=1; off<256; off<<=1){
        int xv = (t>=off)? sh[t-off] : 0; __syncthreads();
        sh[t] += xv; __syncthreads();
    }
    int excl = sh[t] - s;
    if (t==255) bsums[b] = sh[255];
    int4 o; o.x = excl; o.y = excl+v.x; o.z = o.y+v.y; o.w = o.z+v.z;
    *(int4*)(data + base) = o;
}

__global__ __launch_bounds__(256) void k_scan2(int* __restrict__ bsums){
    __shared__ int sh[256];
    int t = threadIdx.x;
    int v0 = bsums[2*t], v1 = bsums[2*t+1];
    int s = v0+v1; sh[t] = s; __syncthreads();
    for (int off=1; off<256; off<<=1){
        int xv = (t>=off)? sh[t-off] : 0; __syncthreads();
        sh[t] += xv; __syncthreads();
    }
    int excl = sh[t] - s;
    bsums[2*t] = excl; bsums[2*t+1] = excl + v0;
}

// ---------------- transpose scanned km -> block-major kmT with bsums folded ----------------
// kmT[blk*BKTS + bucket] = km[bucket*P_BLOCKS + blk] + bsums[bucket]  (global offsets)
__global__ __launch_bounds__(256) void k_tfix(const u32* __restrict__ km, const int* __restrict__ bsums,
        u32* __restrict__ kmT){
    __shared__ u32 tile[32][33];
    int bx = blockIdx.x, by = blockIdx.y;   // bx over 1024/32 blk-groups, by over 512/32 bucket-groups
    int tx = threadIdx.x & 31, ty = threadIdx.x >> 5;
    #pragma unroll
    for (int r=0;r<32;r+=8){
        int bucket = by*32 + ty + r;
        tile[ty+r][tx] = km[(size_t)bucket*P_BLOCKS + bx*32 + tx] + (u32)bsums[bucket];
    }
    __syncthreads();
    #pragma unroll
    for (int r=0;r<32;r+=8)
        kmT[(size_t)(bx*32 + ty + r)*BKTS + by*32 + tx] = tile[tx][ty+r];
}

__global__ __launch_bounds__(256) void k_p2(const int* __restrict__ src, const int* __restrict__ dst,
        const u32* __restrict__ kmT, u32* __restrict__ btab){
    __shared__ u32 lh[BKTS], lofs[BKTS], gofs[BKTS];
    __shared__ u32 stage[4096], tgt[4096];
    __shared__ u32 red[256];
    int t = threadIdx.x, blk = blockIdx.x;
    lh[t] = 0; lh[t+256] = 0;
    __syncthreads();
    u32 pr[16], rk[16]; u16 bk[16];
    int base = blk*4096;
    #pragma unroll
    for (int k=0;k<16;k++){
        int e = base + k*256 + t;
        int d = __builtin_nontemporal_load(dst+e) & (N_NODES-1);
        int s = __builtin_nontemporal_load(src+e) & (N_NODES-1);
        u32 b = (u32)d >> 10;
        bk[k] = (u16)b;
        pr[k] = (u32)(d & 1023) | ((u32)s << 10);
        rk[k] = atomicAdd(&lh[b], 1);
    }
    gofs[t]       = kmT[(size_t)blk*BKTS + t];
    gofs[t+256]   = kmT[(size_t)blk*BKTS + t + 256];
    __syncthreads();
    u32 v0 = lh[2*t], v1 = lh[2*t+1];
    u32 s2 = v0+v1; red[t] = s2; __syncthreads();
    for (int off=1; off<256; off<<=1){
        u32 xv = (t>=off)? red[t-off] : 0; __syncthreads();
        red[t] += xv; __syncthreads();
    }
    u32 excl = red[t] - s2;
    lofs[2*t] = excl; lofs[2*t+1] = excl + v0;
    __syncthreads();
    #pragma unroll
    for (int k=0;k<16;k++){
        u32 p = lofs[bk[k]] + rk[k];
        stage[p] = pr[k];
        tgt[p]   = gofs[bk[k]] + rk[k];
    }
    __syncthreads();
    #pragma unroll
    for (int k=0;k<16;k++){
        int j = k*256 + t;
        btab[tgt[j]] = stage[j];
    }
}

__global__ __launch_bounds__(256) void k_p3(const u32* __restrict__ kmT, const u32* __restrict__ btab,
        int* __restrict__ rowptr, int* __restrict__ ssrc){
    __shared__ u32 fh[DPB], fo[DPB];
    __shared__ u32 red[256];
    __shared__ int sst[CAP];
    int t = threadIdx.x, b = blockIdx.x;
    u32 basep = kmT[b];                                   // blk=0 column = bucket start
    u32 endp  = (b == BKTS-1) ? (u32)N_EDGES : kmT[b+1];
    int cnt = (int)(endp - basep);
    #pragma unroll
    for (int i=t;i<DPB;i+=256) fh[i] = 0;
    __syncthreads();
    for (int j=t; j<cnt; j+=256){
        u32 p = btab[basep + j];
        atomicAdd(&fh[p & 1023], 1);
    }
    __syncthreads();
    u32 v0=fh[4*t], v1=fh[4*t+1], v2=fh[4*t+2], v3=fh[4*t+3];
    u32 s4 = v0+v1+v2+v3; red[t] = s4; __syncthreads();
    for (int off=1; off<256; off<<=1){
        u32 xv = (t>=off)? red[t-off] : 0; __syncthreads();
        red[t] += xv; __syncthreads();
    }
    u32 excl = red[t] - s4;
    fo[4*t]=excl; fo[4*t+1]=excl+v0; fo[4*t+2]=excl+v0+v1; fo[4*t+3]=excl+v0+v1+v2;
    __syncthreads();
    #pragma unroll
    for (int i=t;i<DPB;i+=256) rowptr[b*DPB + i] = (int)(basep + fo[i]);
    if (b == BKTS-1 && t == 0) rowptr[N_NODES] = (int)endp;
    __syncthreads();
    for (int j=t; j<cnt; j+=256){
        u32 p = btab[basep + j];
        u32 pos = atomicAdd(&fo[p & 1023], 1);
        if (pos < (u32)CAP) sst[pos] = (int)(p >> 10);
    }
    __syncthreads();
    for (int j=t; j<cnt; j+=256) ssrc[basep + j] = sst[j];
}

// ---------------- fused: gather1 (2048 blocks) + fc1/fc3 GEMM (1024 blocks, 1:2) ----------------
// XCD-aware (bm,bn) mapping: the 4 bn-tiles of one bm-panel sit at g, g+8, g+16,
// g+24 -> same XCD (bid=3g, XCD=bid%8), co-resident -> A-panel re-reads hit L2.
__global__ __launch_bounds__(256) void k_g1mlp(const int* __restrict__ rowptr, const int* __restrict__ ssrc,
        const u16* __restrict__ h1, const float* __restrict__ ad1, const u32* __restrict__ gkey1,
        const void* __restrict__ b1, const float* __restrict__ prep,
        u16* __restrict__ g1, float* __restrict__ ad2, u32* __restrict__ gkey2,
        const int* __restrict__ flag,
        const void* __restrict__ fing, const u16* __restrict__ Wt1,
        const void* __restrict__ fc1b, const void* __restrict__ bn1, u16* __restrict__ fp1,
        const void* __restrict__ tv, const u16* __restrict__ Wt3,
        const void* __restrict__ fc3b, const void* __restrict__ bn3, u16* __restrict__ tv1){
    __shared__ u16 As[128][40];
    __shared__ u16 Bs[128][40];
    __shared__ float b1s[14], vas[14], vds[14];
    __shared__ float red[256];
    int is32 = *flag;
    int bid = blockIdx.x, t = threadIdx.x;
    if (bid % 3 == 0){
        int g = bid / 3;            // [0,1024)
        int gg = (g < 512) ? g : g - 512;
        int r = gg & 7, q = gg >> 3;
        int bn = (q & 3) * 128;
        int bm = ((q >> 2) * 8 + r) * 128;
        if (g < 512)
            gemm_block(As, Bs, fing, Wt1, fc1b, bn1, fp1, 1024, 1024, 400, 400, 0, 1, 0,
                       1, is32, bm, bn, t);
        else
            gemm_block(As, Bs, tv, Wt3, fc3b, bn3, tv1, 256, 256, 400, 400, 0, 1, 0,
                       1, is32, bm, bn, t);
        return;
    }
    int gb = bid - bid/3 - 1;       // [0,2048)
    if (t < 14) b1s[t] = gload(b1, t, is32);
    else if (t < 28) vas[t-14] = prep[t-14];
    else if (t < 42) vds[t-28] = prep[t-28+14];
    __syncthreads();
    int i = gb*256 + t;
    float adv = ad1[i];
    float M = lrelu(key_fmax(*gkey1) + adv);
    int beg = rowptr[i], end = rowptr[i+1];
    float acc[14] = {0,0,0,0,0,0,0,0,0,0,0,0,0,0};
    float den = 0.f;
    {   // self loop
        const uint4* hp = (const uint4*)(h1 + (size_t)i*16);
        edge_acc(hp[0], hp[1], adv, M, acc, den);
    }
    walk8(ssrc, h1, beg, end, adv, M, acc, den);
    float inv = 1.0f/den;
    float v[14];
    #pragma unroll
    for (int f=0;f<14;f++) v[f] = fmaxf(acc[f]*inv + b1s[f], 0.f);
    float a2=0.f, d2=0.f;
    #pragma unroll
    for (int f=0;f<14;f++){ a2 += v[f]*vas[f]; d2 += v[f]*vds[f]; }
    ad2[i] = d2;
    u32 ou[8];
    #pragma unroll
    for (int p=0;p<7;p++) ou[p] = (u32)f2bf(v[2*p]) | ((u32)f2bf(v[2*p+1])<<16);
    __builtin_memcpy(&ou[7], &a2, 4);
    uint4* gp = (uint4*)(g1 + (size_t)i*16);
    gp[0]=make_uint4(ou[0],ou[1],ou[2],ou[3]);
    gp[1]=make_uint4(ou[4],ou[5],ou[6],ou[7]);
    red[t] = a2; __syncthreads();
    for (int o=128;o;o>>=1){ if (t<o) red[t]=fmaxf(red[t],red[t+o]); __syncthreads(); }
    if (t==0) atomicMax(gkey2, fmax_key(red[0]));
}

// ---------------- fused: gather2 (2048 blocks) + fc2/fc4 GEMM (512 blocks, 1:4) ----------------
__global__ __launch_bounds__(256) void k_g2mlp(const int* __restrict__ rowptr, const int* __restrict__ ssrc,
        const u16* __restrict__ g1, const float* __restrict__ ad2, const u32* __restrict__ gkey2,
        const void* __restrict__ W2, const void* __restrict__ b2, u16* __restrict__ g2,
        const int* __restrict__ flag,
        const u16* __restrict__ fp1, const u16* __restrict__ Wt2,
        const void* __restrict__ fc2b, const void* __restrict__ bn2,
        const u16* __restrict__ tv1, const u16* __restrict__ Wt4,
        const void* __restrict__ fc4b, const void* __restrict__ bn4,
        u16* __restrict__ comb){
    __shared__ u16 As[128][40];
    __shared__ u16 Bs[128][40];
    __shared__ float W2s[448], b2s[32];
    int is32 = *flag;
    int bid = blockIdx.x, t = threadIdx.x;
    if (bid % 5 == 0){
        int g = bid / 5;            // [0,512)
        int gg = (g < 256) ? g : g - 256;
        int r = gg & 7, q = gg >> 3;
        int bn = (q & 1) * 128;
        int bm = ((q >> 1) * 8 + r) * 128;
        if (g < 256)
            gemm_block(As, Bs, fp1, Wt2, fc2b, bn2, comb, 400, 416, 200, 432, 32, 1, 0,
                       0, is32, bm, bn, t);
        else
            gemm_block(As, Bs, tv1, Wt4, fc4b, bn4, comb, 400, 416, 200, 432, 232, 1, 0,
                       0, is32, bm, bn, t);
        return;
    }
    int gb = bid - bid/5 - 1;       // [0,2048)
    for (int idx=t; idx<448; idx+=256) W2s[idx] = gload(W2, idx, is32);
    if (t < 32) b2s[t] = gload(b2, t, is32);
    __syncthreads();
    int i = gb*256 + t;
    float adv = ad2[i];
    float M = lrelu(key_fmax(*gkey2) + adv);
    int beg = rowptr[i], end = rowptr[i+1];
    float acc[14] = {0,0,0,0,0,0,0,0,0,0,0,0,0,0};
    float den = 0.f;
    {
        const uint4* hp = (const uint4*)(g1 + (size_t)i*16);
        edge_acc(hp[0], hp[1], adv, M, acc, den);
    }
    walk8(ssrc, g1, beg, end, adv, M, acc, den);
    float inv = 1.0f/den;
    float an[14];
    #pragma unroll
    for (int f=0;f<14;f++) an[f] = acc[f]*inv;
    uint4* orow = (uint4*)(g2 + (size_t)i*32);
    #pragma unroll
    for (int g=0; g<4; g++){
        u32 ou[4];
        #pragma unroll
        for (int p=0;p<4;p++){
            int j0 = g*8 + 2*p;
            float va_ = b2s[j0], vb_ = b2s[j0+1];
            #pragma unroll
            for (int k=0;k<14;k++){ va_ += an[k]*W2s[k*32+j0]; vb_ += an[k]*W2s[k*32+j0+1]; }
            va_ = fmaxf(va_, 0.f); vb_ = fmaxf(vb_, 0.f);
            ou[p] = (u32)f2bf(va_) | ((u32)f2bf(vb_)<<16);
        }
        orow[g] = make_uint4(ou[0],ou[1],ou[2],ou[3]);
    }
}

// ---------------- pool (batch is sorted; binary search per graph) ----------------
__device__ __forceinline__ int lbound(const int* __restrict__ a, int n, int v){
    int lo=0, hi=n;
    while (lo < hi){ int m = (lo+hi)>>1; if (a[m] < v) lo = m+1; else hi = m; }
    return lo;
}

__global__ __launch_bounds__(64) void k_pool(const u16* __restrict__ g2, const int* __restrict__ batch,
        u16* __restrict__ comb, int N_){
    int b = blockIdx.x;
    int t = threadIdx.x, f = t & 31, half = t >> 5;
    int lo = lbound(batch, N_, b);
    int hi = lbound(batch, N_, b+1);
    float acc = 0.f;
    for (int i = lo + half; i < hi; i += 2) acc += bf2f(g2[(size_t)i*32 + f]);
    acc += __shfl_xor(acc, 32);
    if (t < 32) comb[(size_t)b*432 + f] = f2bf(acc);
}

// ---------------- fcc1 GEMM with fused fcc2 epilogue -> FP32 output [16384] ----------------
__global__ __launch_bounds__(256) void k_gemmfin(const u16* __restrict__ A, const u16* __restrict__ Wt,
        const void* __restrict__ bias, const void* __restrict__ bnp,
        const void* __restrict__ w2, const void* __restrict__ b2,
        float* __restrict__ outp, const int* __restrict__ flag){
    __shared__ u16 As[128][40];
    __shared__ u16 Bs[128][40];
    __shared__ float wf[100];
    __shared__ float rowacc[128];
    int is32 = *flag;
    int t = threadIdx.x;
    const int K = 432, Kp = 448, Nc = 100;
    if (t < 100) wf[t] = gload(w2, t, is32);
    if (t < 128) rowacc[t] = 0.f;
    int lane = t & 63, wave = t >> 6;
    int bm = blockIdx.x * 128;
    int mt = (wave & 1) * 64, nt = (wave >> 1) * 64;
    int quad = lane >> 4, fr = lane & 15;

    f32x4 zero = {0.f, 0.f, 0.f, 0.f};
    f32x4 acc[4][4];
    #pragma unroll
    for (int i=0;i<4;i++)
        #pragma unroll
        for (int j=0;j<4;j++) acc[i][j] = zero;

    int srow0 = t >> 2;
    int scol = (t & 3) * 8;

    for (int k0 = 0; k0 < Kp; k0 += 32){
        #pragma unroll
        for (int h2_=0; h2_<2; h2_++){
            int row = srow0 + h2_*64;
            int gk = k0 + scol;
            uint4 av = make_uint4(0,0,0,0);
            if (gk + 8 <= K) av = *(const uint4*)(A + (size_t)(bm+row)*K + gk);
            *(uint4*)(&As[row][scol]) = av;
            uint4 bv = make_uint4(0,0,0,0);
            if (row < Nc) bv = *(const uint4*)(Wt + (size_t)row*Kp + gk);
            *(uint4*)(&Bs[row][scol]) = bv;
        }
        __syncthreads();
        bf16x8 af[4], bfr[4];
        #pragma unroll
        for (int i=0;i<4;i++) af[i] = *(const bf16x8*)(&As[mt + i*16 + fr][quad*8]);
        #pragma unroll
        for (int j=0;j<4;j++) bfr[j] = *(const bf16x8*)(&Bs[nt + j*16 + fr][quad*8]);
        #pragma unroll
        for (int i=0;i<4;i++)
            #pragma unroll
            for (int j=0;j<4;j++)
                acc[i][j] = __builtin_amdgcn_mfma_f32_16x16x32_bf16(af[i], bfr[j], acc[i][j], 0, 0, 0);
        __syncthreads();
    }

    #pragma unroll
    for (int j=0;j<4;j++){
        int gn = nt + j*16 + fr;
        if (gn >= Nc) continue;
        float bb = gload(bias, gn, is32);
        float gm_ = gload(bnp, gn, is32), bt = gload(bnp, Nc+gn, is32);
        float mn = gload(bnp, 2*Nc+gn, is32), vr = gload(bnp, 3*Nc+gn, is32);
        float scale = gm_ * rsqrtf(vr + 1e-5f);
        float shift = (bb - mn)*scale + bt;
        float wgn = wf[gn];
        #pragma unroll
        for (int i=0;i<4;i++){
            #pragma unroll
            for (int r=0;r<4;r++){
                int lgm = mt + i*16 + quad*4 + r;
                float v = fmaxf(acc[i][j][r]*scale + shift, 0.f);
                atomicAdd(&rowacc[lgm], v*wgn);
            }
        }
    }
    __syncthreads();
    if (t < 128) outp[bm + t] = rowacc[t] + gload(b2, 0, is32);
}

extern "C" void kernel_launch(void* const* d_in, const int* in_sizes, int n_in,
                              void* d_out, int out_size, void* d_ws, size_t ws_size,
                              hipStream_t stream){
    const int N = N_NODES, E = N_EDGES;
    const void* x    = d_in[0];
    const int* ei   = (const int*)d_in[1];
    const int* srcA = ei;
    const int* dstA = ei + E;
    const int* batch= (const int*)d_in[2];
    const void* fing = d_in[3];
    const void* tv   = d_in[4];
    const void* W1   = d_in[5];
    const void* as1w = d_in[6];
    const void* ad1w = d_in[7];
    const void* b1   = d_in[8];
    const void* W2   = d_in[9];
    const void* as2w = d_in[10];
    const void* ad2w = d_in[11];
    const void* b2   = d_in[12];
    const void* fc1w = d_in[13]; const void* fc1b = d_in[14]; const void* bn1 = d_in[15];
    const void* fc2w = d_in[16]; const void* fc2b = d_in[17]; const void* bn2 = d_in[18];
    const void* fc3w = d_in[19]; const void* fc3b = d_in[20]; const void* bn3 = d_in[21];
    const void* fc4w = d_in[22]; const void* fc4b = d_in[23]; const void* bn4 = d_in[24];
    const void* fccw = d_in[25]; const void* fccb = d_in[26]; const void* bnc = d_in[27];
    const void* fcc2w= d_in[28]; const void* fcc2b= d_in[29];

    char* ws = (char*)d_ws;
    size_t off = 0;
    auto alloc = [&](size_t bytes)->char*{ char* p = ws + off; off = (off + bytes + 255) & ~(size_t)255; return p; };
    int*  flagp  = (int*)alloc(256);          // [0]=dtype; [1]=gkey1; [2]=gkey2; +16B: prep[28]
    u32*  gkey1  = (u32*)flagp + 1;
    u32*  gkey2  = (u32*)flagp + 2;
    float* prep  = (float*)((char*)flagp + 16);
    int*  rowptr = (int*)alloc((size_t)(N+1)*4);
    int*  bsums  = (int*)alloc(513*4);
    u32*  tbl_bm = (u32*)alloc((size_t)BKTS*P_BLOCKS*4);
    u32*  tbl_km = (u32*)alloc(((size_t)BKTS*P_BLOCKS+1)*4);
    u32*  kmT    = (u32*)alloc((size_t)BKTS*P_BLOCKS*4);   // 2 MB, block-major, bsums folded
    int*  ssrc   = (int*)alloc((size_t)E*4);       // 16 MB
    u16*  h1     = (u16*)alloc((size_t)N*16*2);    // 16.8 MB; comb aliases after g1mlp
    u16*  g1     = (u16*)alloc((size_t)N*16*2);    // 16.8 MB
    float* ad1_  = (float*)alloc((size_t)N*4);
    float* ad2_  = (float*)alloc((size_t)N*4);
    char* scr32  = alloc((size_t)N*32*2);          // 33.6 MB: btab -> g2
    u16*  Wt1    = (u16*)alloc((size_t)400*1024*2);
    u16*  Wt2    = (u16*)alloc((size_t)200*416*2);
    u16*  Wt3    = (u16*)alloc((size_t)400*256*2);
    u16*  Wt4    = (u16*)alloc((size_t)200*416*2);
    u16*  Wtc    = (u16*)alloc((size_t)100*448*2);
    u16*  fp1    = (u16*)alloc((size_t)N_GRAPH*400*2);   // 13.1 MB (written during g1mlp)
    u16*  tv1    = (u16*)alloc((size_t)N_GRAPH*400*2);   // 13.1 MB
    u32*  btab   = (u32*)scr32;                     // 16 MB during CSR build
    u16*  g2     = (u16*)scr32;                     // N*32 bf16 after gather2
    u16*  comb   = (u16*)h1;                        // 14.2 MB; h1 dead after g1mlp

    (void)hipMemsetAsync(flagp, 0, 256, stream);

    k_detect <<<1, 256, 0, stream>>>((const u32*)x, flagp, W2, as2w, ad2w, prep);

    // CSR p1 + weight transposes + linear1 in one launch
    k_p1t  <<<P_BLOCKS + TTOT + LBLK, 256, 0, stream>>>(dstA, tbl_bm,
                 fc1w, fc2w, fc3w, fc4w, fccw, Wt1, Wt2, Wt3, Wt4, Wtc, flagp,
                 x, W1, as1w, ad1w, h1, ad1_, gkey1);
    k_ttbl <<<dim3(32,16), 256, 0, stream>>>(tbl_bm, tbl_km);
    k_scan1<<<512,  256, 0, stream>>>((int*)tbl_km, bsums);
    k_scan2<<<1,    256, 0, stream>>>(bsums);
    k_tfix <<<dim3(32,16), 256, 0, stream>>>(tbl_km, bsums, kmT);
    k_p2   <<<P_BLOCKS, 256, 0, stream>>>(srcA, dstA, kmT, btab);
    k_p3   <<<BKTS, 256, 0, stream>>>(kmT, btab, rowptr, ssrc);

    // gather1 (2048 blocks) + fc1/fc3 single-tile GEMMs (1024 blocks), 1:2, XCD-grouped
    k_g1mlp <<<3072, 256, 0, stream>>>(rowptr, ssrc, h1, ad1_, gkey1, b1, prep, g1, ad2_, gkey2, flagp,
                                       fing, Wt1, fc1b, bn1, fp1,
                                       tv,   Wt3, fc3b, bn3, tv1);
    // gather2 (2048 blocks) + fc2/fc4 single-tile GEMMs (512 blocks), 1:4, XCD-grouped
    k_g2mlp <<<2560, 256, 0, stream>>>(rowptr, ssrc, g1, ad2_, gkey2, W2, b2, g2, flagp,
                                       fp1, Wt2, fc2b, bn2,
                                       tv1, Wt4, fc4b, bn4, comb);
    k_pool   <<<N_GRAPH, 64, 0, stream>>>(g2, batch, comb, N);

    // fcc1 GEMM + fused fcc2 -> d_out
    k_gemmfin<<<128, 256, 0, stream>>>(comb, Wtc, fccb, bnc, fcc2w, fcc2b, (float*)d_out, flagp);
}

// Round 11
// 628.077 us; speedup vs baseline: 1.0290x; 1.0290x over previous
//
#include <hip/hip_runtime.h>

typedef unsigned short u16;
typedef unsigned int u32;
typedef __attribute__((ext_vector_type(8))) short bf16x8;
typedef __attribute__((ext_vector_type(4))) float f32x4;

#define N_NODES 524288
#define N_EDGES 4194304
#define N_GRAPH 16384
#define P_BLOCKS 1024          // P1/P2 blocks; 4096 edges each
#define BKTS 512               // coarse buckets = dst>>10
#define DPB 1024               // dsts per bucket
#define CAP 8960               // max edges per bucket
#define TTOT 2825              // transpose blocks: 723200/256
#define LBLK 2048              // linear1 blocks: N/256

__device__ __forceinline__ float bf2f(u16 u){ u32 x=((u32)u)<<16; float f; __builtin_memcpy(&f,&x,4); return f; }
__device__ __forceinline__ float lo2f(u32 u){ u32 x=u<<16; float f; __builtin_memcpy(&f,&x,4); return f; }
__device__ __forceinline__ float hi2f(u32 u){ u32 x=u&0xffff0000u; float f; __builtin_memcpy(&f,&x,4); return f; }
__device__ __forceinline__ u16 f2bf(float f){ u32 x; __builtin_memcpy(&x,&f,4); return (u16)((x + 0x7fffu + ((x>>16)&1u))>>16); }
__device__ __forceinline__ float lrelu(float e){ return e>0.f? e : 0.2f*e; }
__device__ __forceinline__ float gload(const void* p, int i, int is32){
    return is32 ? ((const float*)p)[i] : bf2f(((const u16*)p)[i]);
}
__device__ __forceinline__ u32 fmax_key(float f){ u32 u; __builtin_memcpy(&u,&f,4); return (u>>31)? ~u : (u|0x80000000u); }
__device__ __forceinline__ float key_fmax(u32 k){ u32 u = (k>>31)? (k^0x80000000u) : ~k; float f; __builtin_memcpy(&f,&u,4); return f; }

// accumulate one edge given its 32B row (14 bf16 + fp32 score in q1.w)
__device__ __forceinline__ void edge_acc(uint4 q0, uint4 q1, float adv, float M,
        float* acc, float& den){
    float as_; __builtin_memcpy(&as_, &q1.w, 4);
    float w = __expf(lrelu(as_ + adv) - M); den += w;
    u32 u[7] = {q0.x,q0.y,q0.z,q0.w,q1.x,q1.y,q1.z};
    #pragma unroll
    for (int f=0;f<14;f++){ u32 uu=u[f>>1]; acc[f] += w*((f&1)? hi2f(uu):lo2f(uu)); }
}

// ---------------- 8-deep edge walk, 1 lane per dst, clamped last batch ----------------
__device__ __forceinline__ void walk8(const int* __restrict__ ssrc, const u16* __restrict__ hsrc,
        int beg, int end, float adv, float M, float* acc, float& den){
    for (int j = beg; j < end; j += 8){
        int s8[8];
        #pragma unroll
        for (int k=0;k<8;k++){
            int e = j + k;
            s8[k] = __builtin_nontemporal_load(ssrc + ((e < end) ? e : (end-1)));
        }
        uint4 r0[8], r1[8];
        #pragma unroll
        for (int k=0;k<8;k++){
            const uint4* hp = (const uint4*)(hsrc + (size_t)s8[k]*16);
            r0[k] = hp[0]; r1[k] = hp[1];
        }
        int m = end - j;
        #pragma unroll
        for (int k=0;k<8;k++) if (k < m) edge_acc(r0[k], r1[k], adv, M, acc, den);
    }
}

// ---------------- GEMM block body (bf16 MFMA, 128x128 tile), A may be raw fp32 input ----------------
__device__ __forceinline__ void gemm_block(u16 (*As)[40], u16 (*Bs)[40],
        const void* __restrict__ A, const u16* __restrict__ Wt,
        const void* __restrict__ bias, const void* __restrict__ bnp, void* __restrict__ out,
        int K, int Kp, int Nc, int ostride, int ooff, int do_relu,
        int out32, int araw, int is32, int bm, int bn, int t){
    int af32 = araw && is32;     // A is raw fp32 input -> cast during staging
    int lane = t & 63, wave = t >> 6;
    int mt = (wave & 1) * 64, nt = (wave >> 1) * 64;
    int quad = lane >> 4, fr = lane & 15;

    f32x4 zero = {0.f, 0.f, 0.f, 0.f};
    f32x4 acc[4][4];
    #pragma unroll
    for (int i=0;i<4;i++)
        #pragma unroll
        for (int j=0;j<4;j++) acc[i][j] = zero;

    int srow0 = t >> 2;
    int scol = (t & 3) * 8;

    for (int k0 = 0; k0 < Kp; k0 += 32){
        #pragma unroll
        for (int h2_=0; h2_<2; h2_++){
            int row = srow0 + h2_*64;
            int gk = k0 + scol;
            uint4 av = make_uint4(0,0,0,0);
            if (gk + 8 <= K){
                if (af32){
                    const float* ap = (const float*)A + (size_t)(bm+row)*K + gk;
                    float4 a0 = *(const float4*)ap, a1 = *(const float4*)(ap+4);
                    av.x = (u32)f2bf(a0.x) | ((u32)f2bf(a0.y)<<16);
                    av.y = (u32)f2bf(a0.z) | ((u32)f2bf(a0.w)<<16);
                    av.z = (u32)f2bf(a1.x) | ((u32)f2bf(a1.y)<<16);
                    av.w = (u32)f2bf(a1.z) | ((u32)f2bf(a1.w)<<16);
                } else {
                    av = *(const uint4*)((const u16*)A + (size_t)(bm+row)*K + gk);
                }
            }
            *(uint4*)(&As[row][scol]) = av;
            uint4 bv = make_uint4(0,0,0,0);
            if (bn + row < Nc) bv = *(const uint4*)(Wt + (size_t)(bn+row)*Kp + gk);
            *(uint4*)(&Bs[row][scol]) = bv;
        }
        __syncthreads();
        bf16x8 af[4], bfr[4];
        #pragma unroll
        for (int i=0;i<4;i++) af[i] = *(const bf16x8*)(&As[mt + i*16 + fr][quad*8]);
        #pragma unroll
        for (int j=0;j<4;j++) bfr[j] = *(const bf16x8*)(&Bs[nt + j*16 + fr][quad*8]);
        #pragma unroll
        for (int i=0;i<4;i++)
            #pragma unroll
            for (int j=0;j<4;j++)
                acc[i][j] = __builtin_amdgcn_mfma_f32_16x16x32_bf16(af[i], bfr[j], acc[i][j], 0, 0, 0);
        __syncthreads();
    }

    #pragma unroll
    for (int j=0;j<4;j++){
        int gn = bn + nt + j*16 + fr;
        if (gn >= Nc) continue;
        float bb = gload(bias, gn, is32);
        float scale = 1.f, shift = bb;
        if (bnp){
            float gm_ = gload(bnp, gn, is32), bt = gload(bnp, Nc+gn, is32);
            float mn = gload(bnp, 2*Nc+gn, is32), vr = gload(bnp, 3*Nc+gn, is32);
            scale = gm_ * rsqrtf(vr + 1e-5f);
            shift = (bb - mn)*scale + bt;
        }
        #pragma unroll
        for (int i=0;i<4;i++){
            #pragma unroll
            for (int r=0;r<4;r++){
                int gm = bm + mt + i*16 + quad*4 + r;
                float v = acc[i][j][r]*scale + shift;
                if (do_relu) v = fmaxf(v, 0.f);
                size_t oidx = (size_t)gm*ostride + ooff + gn;
                if (out32) ((float*)out)[oidx] = v;
                else       ((u16*)out)[oidx] = f2bf(v);
            }
        }
    }
}

// ---------------- input dtype detector + prep (va = W2 @ a_s2, vd = W2 @ a_d2) ----------------
__global__ __launch_bounds__(256) void k_detect(const u32* __restrict__ x, int* __restrict__ flag,
        const void* __restrict__ W2, const void* __restrict__ asw, const void* __restrict__ adw,
        float* __restrict__ prep){
    __shared__ int cnt, s32;
    int t = threadIdx.x;
    if (t==0) cnt = 0;
    __syncthreads();
    int c = 0;
    for (int i = t; i < 1024; i += 256){
        u32 e = (x[i] >> 7) & 0xFF;
        if (e >= 110 && e <= 140) c++;
    }
    atomicAdd(&cnt, c);
    __syncthreads();
    if (t==0){ int f = (cnt < 512) ? 1 : 0; *flag = f; s32 = f; }
    __syncthreads();
    int is32 = s32;
    if (t < 28){
        int j = t % 14, which = t / 14;
        const void* av = which ? adw : asw;
        float s = 0.f;
        #pragma unroll
        for (int k=0;k<32;k++) s += gload(W2, j*32+k, is32) * gload(av, k, is32);
        prep[which*14 + j] = s;
    }
}

// ---------------- CSR p1 + 5 weight transposes + GAT layer-1 node linear, one launch ----------------
__global__ __launch_bounds__(256) void k_p1t(const int* __restrict__ dst, u32* __restrict__ tbl_bm,
        const void* __restrict__ Wa, const void* __restrict__ Wb, const void* __restrict__ Wc,
        const void* __restrict__ Wd, const void* __restrict__ We,
        u16* __restrict__ Ta, u16* __restrict__ Tb, u16* __restrict__ Tc,
        u16* __restrict__ Td, u16* __restrict__ Te, const int* __restrict__ flag,
        const void* __restrict__ x, const void* __restrict__ W1,
        const void* __restrict__ asw, const void* __restrict__ adw,
        u16* __restrict__ h1, float* __restrict__ ad1, u32* __restrict__ gkey){
    __shared__ u32 lh[BKTS];
    __shared__ float Wf[196], av14[14], dv14[14];
    __shared__ float red[256];
    int bid = blockIdx.x, t = threadIdx.x;
    if (bid >= P_BLOCKS + TTOT){
        // ---- role 3: linear1 ----
        int is32 = *flag;
        if (t < 196) Wf[t] = gload(W1, t, is32);
        else if (t < 210) av14[t-196] = gload(asw, t-196, is32);
        else if (t < 224) dv14[t-210] = gload(adw, t-210, is32);
        __syncthreads();
        int i = (bid - P_BLOCKS - TTOT)*256 + t;
        float xv[14];
        if (is32){
            const float* xr = (const float*)x + (size_t)i*14;
            #pragma unroll
            for (int k=0;k<14;k++) xv[k] = xr[k];
        } else {
            const u32* xr = (const u32*)((const u16*)x + (size_t)i*14);
            #pragma unroll
            for (int p=0;p<7;p++){ u32 u = xr[p]; xv[2*p]=lo2f(u); xv[2*p+1]=hi2f(u); }
        }
        float h[14];
        #pragma unroll
        for (int j=0;j<14;j++){ float s=0.f;
            #pragma unroll
            for (int k=0;k<14;k++) s += xv[k]*Wf[k*14+j];
            h[j]=s; }
        float a=0.f, d=0.f;
        #pragma unroll
        for (int j=0;j<14;j++){ a += h[j]*av14[j]; d += h[j]*dv14[j]; }
        ad1[i]=d;
        u32 ou[8];
        #pragma unroll
        for (int p=0;p<7;p++) ou[p] = (u32)f2bf(h[2*p]) | ((u32)f2bf(h[2*p+1])<<16);
        __builtin_memcpy(&ou[7], &a, 4);
        uint4* hp = (uint4*)(h1 + (size_t)i*16);
        hp[0] = make_uint4(ou[0],ou[1],ou[2],ou[3]);
        hp[1] = make_uint4(ou[4],ou[5],ou[6],ou[7]);
        red[t] = a; __syncthreads();
        for (int o=128;o;o>>=1){ if (t<o) red[t]=fmaxf(red[t],red[t+o]); __syncthreads(); }
        if (t==0) atomicMax(gkey, fmax_key(red[0]));
        return;
    }
    if (bid >= P_BLOCKS){
        // ---- role 2: weight transpose ----
        int is32 = *flag;
        int loc = (bid - P_BLOCKS)*256 + t;
        const int n1=400*1024, n2=200*416, n3=400*256, n4=200*416, n5=100*448;
        const void* W; u16* T; int K, Kp, Nc;
        if (loc < n1){ W=Wa; T=Ta; K=1024; Kp=1024; Nc=400; }
        else if ((loc-=n1) < n2){ W=Wb; T=Tb; K=400; Kp=416; Nc=200; }
        else if ((loc-=n2) < n3){ W=Wc; T=Tc; K=256; Kp=256; Nc=400; }
        else if ((loc-=n3) < n4){ W=Wd; T=Td; K=400; Kp=416; Nc=200; }
        else if ((loc-=n4) < n5){ W=We; T=Te; K=432; Kp=448; Nc=100; }
        else return;
        int n = loc / Kp, k = loc - n*Kp;
        T[loc] = (k < K) ? f2bf(gload(W, k*Nc + n, is32)) : (u16)0;
        return;
    }
    // ---- role 1: CSR p1 histogram ----
    int blk = bid;
    lh[t] = 0; lh[t+256] = 0;
    __syncthreads();
    int base = blk*4096;
    #pragma unroll
    for (int k=0;k<16;k++){
        int d = __builtin_nontemporal_load(dst + base + k*256 + t) & (N_NODES-1);
        atomicAdd(&lh[d>>10], 1);
    }
    __syncthreads();
    tbl_bm[blk*BKTS + t]       = lh[t];
    tbl_bm[blk*BKTS + t + 256] = lh[t+256];
}

__global__ __launch_bounds__(256) void k_ttbl(const u32* __restrict__ bm, u32* __restrict__ km){
    __shared__ u32 tile[32][33];
    int bx = blockIdx.x, by = blockIdx.y;
    int tx = threadIdx.x & 31, ty = threadIdx.x >> 5;
    #pragma unroll
    for (int r=0;r<32;r+=8)
        tile[ty+r][tx] = bm[(bx*32 + ty + r)*BKTS + by*32 + tx];
    __syncthreads();
    #pragma unroll
    for (int r=0;r<32;r+=8)
        km[(by*32 + ty + r)*P_BLOCKS + bx*32 + tx] = tile[tx][ty+r];
}

__global__ __launch_bounds__(256) void k_scan1(int* __restrict__ data, int* __restrict__ bsums){
    __shared__ int sh[256];
    int b = blockIdx.x, t = threadIdx.x;
    int base = b*1024 + t*4;
    int4 v = *(const int4*)(data + base);
    int s = v.x+v.y+v.z+v.w;
    sh[t] = s; __syncthreads();
    for (int off=1; off<256; off<<=1){
        int xv = (t>=off)? sh[t-off] : 0; __syncthreads();
        sh[t] += xv; __syncthreads();
    }
    int excl = sh[t] - s;
    if (t==255) bsums[b] = sh[255];
    int4 o; o.x = excl; o.y = excl+v.x; o.z = o.y+v.y; o.w = o.z+v.z;
    *(int4*)(data + base) = o;
}

__global__ __launch_bounds__(256) void k_scan2(int* __restrict__ bsums){
    __shared__ int sh[256];
    int t = threadIdx.x;
    int v0 = bsums[2*t], v1 = bsums[2*t+1];
    int s = v0+v1; sh[t] = s; __syncthreads();
    for (int off=1; off<256; off<<=1){
        int xv = (t>=off)? sh[t-off] : 0; __syncthreads();
        sh[t] += xv; __syncthreads();
    }
    int excl = sh[t] - s;
    bsums[2*t] = excl; bsums[2*t+1] = excl + v0;
}

__global__ __launch_bounds__(256) void k_scan3(int* __restrict__ scan, const int* __restrict__ bsums, int N_, int E_){
    int i = blockIdx.x*256 + threadIdx.x;
    if (i < N_) scan[i] += bsums[i>>10];
    if (i == 0) scan[N_] = E_;
}

__global__ __launch_bounds__(256) void k_p2(const int* __restrict__ src, const int* __restrict__ dst,
        const u32* __restrict__ km, u32* __restrict__ btab){
    __shared__ u32 lh[BKTS], lofs[BKTS], gofs[BKTS];
    __shared__ u32 stage[4096], tgt[4096];
    __shared__ u32 red[256];
    int t = threadIdx.x, blk = blockIdx.x;
    lh[t] = 0; lh[t+256] = 0;
    __syncthreads();
    u32 pr[16], rk[16]; u16 bk[16];
    int base = blk*4096;
    #pragma unroll
    for (int k=0;k<16;k++){
        int e = base + k*256 + t;
        int d = __builtin_nontemporal_load(dst+e) & (N_NODES-1);
        int s = __builtin_nontemporal_load(src+e) & (N_NODES-1);
        u32 b = (u32)d >> 10;
        bk[k] = (u16)b;
        pr[k] = (u32)(d & 1023) | ((u32)s << 10);
        rk[k] = atomicAdd(&lh[b], 1);
    }
    gofs[t]       = km[(size_t)t*P_BLOCKS + blk];
    gofs[t+256]   = km[(size_t)(t+256)*P_BLOCKS + blk];
    __syncthreads();
    u32 v0 = lh[2*t], v1 = lh[2*t+1];
    u32 s2 = v0+v1; red[t] = s2; __syncthreads();
    for (int off=1; off<256; off<<=1){
        u32 xv = (t>=off)? red[t-off] : 0; __syncthreads();
        red[t] += xv; __syncthreads();
    }
    u32 excl = red[t] - s2;
    lofs[2*t] = excl; lofs[2*t+1] = excl + v0;
    __syncthreads();
    #pragma unroll
    for (int k=0;k<16;k++){
        u32 p = lofs[bk[k]] + rk[k];
        stage[p] = pr[k];
        tgt[p]   = gofs[bk[k]] + rk[k];
    }
    __syncthreads();
    #pragma unroll
    for (int k=0;k<16;k++){
        int j = k*256 + t;
        btab[tgt[j]] = stage[j];
    }
}

__global__ __launch_bounds__(256) void k_p3(const u32* __restrict__ km, const u32* __restrict__ btab,
        int* __restrict__ rowptr, int* __restrict__ ssrc){
    __shared__ u32 fh[DPB], fo[DPB];
    __shared__ u32 red[256];
    __shared__ int sst[CAP];
    int t = threadIdx.x, b = blockIdx.x;
    u32 basep = km[(size_t)b*P_BLOCKS];
    u32 endp  = km[(size_t)(b+1)*P_BLOCKS];
    int cnt = (int)(endp - basep);
    #pragma unroll
    for (int i=t;i<DPB;i+=256) fh[i] = 0;
    __syncthreads();
    for (int j=t; j<cnt; j+=256){
        u32 p = btab[basep + j];
        atomicAdd(&fh[p & 1023], 1);
    }
    __syncthreads();
    u32 v0=fh[4*t], v1=fh[4*t+1], v2=fh[4*t+2], v3=fh[4*t+3];
    u32 s4 = v0+v1+v2+v3; red[t] = s4; __syncthreads();
    for (int off=1; off<256; off<<=1){
        u32 xv = (t>=off)? red[t-off] : 0; __syncthreads();
        red[t] += xv; __syncthreads();
    }
    u32 excl = red[t] - s4;
    fo[4*t]=excl; fo[4*t+1]=excl+v0; fo[4*t+2]=excl+v0+v1; fo[4*t+3]=excl+v0+v1+v2;
    __syncthreads();
    #pragma unroll
    for (int i=t;i<DPB;i+=256) rowptr[b*DPB + i] = (int)(basep + fo[i]);
    if (b == BKTS-1 && t == 0) rowptr[N_NODES] = (int)endp;
    __syncthreads();
    for (int j=t; j<cnt; j+=256){
        u32 p = btab[basep + j];
        u32 pos = atomicAdd(&fo[p & 1023], 1);
        if (pos < (u32)CAP) sst[pos] = (int)(p >> 10);
    }
    __syncthreads();
    for (int j=t; j<cnt; j+=256) ssrc[basep + j] = sst[j];
}

// ---------------- fused: gather1 (2048 blocks) + fc1/fc3 GEMM (1024 blocks, 1:2) ----------------
// XCD-aware (bm,bn) mapping: the 4 bn-tiles of one bm-panel sit at g, g+8, g+16,
// g+24 -> same XCD (bid=3g, XCD=bid%8), co-resident -> A-panel re-reads hit L2.
__global__ __launch_bounds__(256) void k_g1mlp(const int* __restrict__ rowptr, const int* __restrict__ ssrc,
        const u16* __restrict__ h1, const float* __restrict__ ad1, const u32* __restrict__ gkey1,
        const void* __restrict__ b1, const float* __restrict__ prep,
        u16* __restrict__ g1, float* __restrict__ ad2, u32* __restrict__ gkey2,
        const int* __restrict__ flag,
        const void* __restrict__ fing, const u16* __restrict__ Wt1,
        const void* __restrict__ fc1b, const void* __restrict__ bn1, u16* __restrict__ fp1,
        const void* __restrict__ tv, const u16* __restrict__ Wt3,
        const void* __restrict__ fc3b, const void* __restrict__ bn3, u16* __restrict__ tv1){
    __shared__ u16 As[128][40];
    __shared__ u16 Bs[128][40];
    __shared__ float b1s[14], vas[14], vds[14];
    __shared__ float red[256];
    int is32 = *flag;
    int bid = blockIdx.x, t = threadIdx.x;
    if (bid % 3 == 0){
        int g = bid / 3;            // [0,1024)
        int gg = (g < 512) ? g : g - 512;
        int r = gg & 7, q = gg >> 3;
        int bn = (q & 3) * 128;
        int bm = ((q >> 2) * 8 + r) * 128;
        if (g < 512)
            gemm_block(As, Bs, fing, Wt1, fc1b, bn1, fp1, 1024, 1024, 400, 400, 0, 1, 0,
                       1, is32, bm, bn, t);
        else
            gemm_block(As, Bs, tv, Wt3, fc3b, bn3, tv1, 256, 256, 400, 400, 0, 1, 0,
                       1, is32, bm, bn, t);
        return;
    }
    int gb = bid - bid/3 - 1;       // [0,2048)
    if (t < 14) b1s[t] = gload(b1, t, is32);
    else if (t < 28) vas[t-14] = prep[t-14];
    else if (t < 42) vds[t-28] = prep[t-28+14];
    __syncthreads();
    int i = gb*256 + t;
    float adv = ad1[i];
    float M = lrelu(key_fmax(*gkey1) + adv);
    int beg = rowptr[i], end = rowptr[i+1];
    float acc[14] = {0,0,0,0,0,0,0,0,0,0,0,0,0,0};
    float den = 0.f;
    {   // self loop
        const uint4* hp = (const uint4*)(h1 + (size_t)i*16);
        edge_acc(hp[0], hp[1], adv, M, acc, den);
    }
    walk8(ssrc, h1, beg, end, adv, M, acc, den);
    float inv = 1.0f/den;
    float v[14];
    #pragma unroll
    for (int f=0;f<14;f++) v[f] = fmaxf(acc[f]*inv + b1s[f], 0.f);
    float a2=0.f, d2=0.f;
    #pragma unroll
    for (int f=0;f<14;f++){ a2 += v[f]*vas[f]; d2 += v[f]*vds[f]; }
    ad2[i] = d2;
    u32 ou[8];
    #pragma unroll
    for (int p=0;p<7;p++) ou[p] = (u32)f2bf(v[2*p]) | ((u32)f2bf(v[2*p+1])<<16);
    __builtin_memcpy(&ou[7], &a2, 4);
    uint4* gp = (uint4*)(g1 + (size_t)i*16);
    gp[0]=make_uint4(ou[0],ou[1],ou[2],ou[3]);
    gp[1]=make_uint4(ou[4],ou[5],ou[6],ou[7]);
    red[t] = a2; __syncthreads();
    for (int o=128;o;o>>=1){ if (t<o) red[t]=fmaxf(red[t],red[t+o]); __syncthreads(); }
    if (t==0) atomicMax(gkey2, fmax_key(red[0]));
}

// ---------------- fused: gather2 (2048 blocks) + fc2/fc4 GEMM (512 blocks, 1:4) ----------------
__global__ __launch_bounds__(256) void k_g2mlp(const int* __restrict__ rowptr, const int* __restrict__ ssrc,
        const u16* __restrict__ g1, const float* __restrict__ ad2, const u32* __restrict__ gkey2,
        const void* __restrict__ W2, const void* __restrict__ b2, u16* __restrict__ g2,
        const int* __restrict__ flag,
        const u16* __restrict__ fp1, const u16* __restrict__ Wt2,
        const void* __restrict__ fc2b, const void* __restrict__ bn2,
        const u16* __restrict__ tv1, const u16* __restrict__ Wt4,
        const void* __restrict__ fc4b, const void* __restrict__ bn4,
        u16* __restrict__ comb){
    __shared__ u16 As[128][40];
    __shared__ u16 Bs[128][40];
    __shared__ float W2s[448], b2s[32];
    int is32 = *flag;
    int bid = blockIdx.x, t = threadIdx.x;
    if (bid % 5 == 0){
        int g = bid / 5;            // [0,512)
        int gg = (g < 256) ? g : g - 256;
        int r = gg & 7, q = gg >> 3;
        int bn = (q & 1) * 128;
        int bm = ((q >> 1) * 8 + r) * 128;
        if (g < 256)
            gemm_block(As, Bs, fp1, Wt2, fc2b, bn2, comb, 400, 416, 200, 432, 32, 1, 0,
                       0, is32, bm, bn, t);
        else
            gemm_block(As, Bs, tv1, Wt4, fc4b, bn4, comb, 400, 416, 200, 432, 232, 1, 0,
                       0, is32, bm, bn, t);
        return;
    }
    int gb = bid - bid/5 - 1;       // [0,2048)
    for (int idx=t; idx<448; idx+=256) W2s[idx] = gload(W2, idx, is32);
    if (t < 32) b2s[t] = gload(b2, t, is32);
    __syncthreads();
    int i = gb*256 + t;
    float adv = ad2[i];
    float M = lrelu(key_fmax(*gkey2) + adv);
    int beg = rowptr[i], end = rowptr[i+1];
    float acc[14] = {0,0,0,0,0,0,0,0,0,0,0,0,0,0};
    float den = 0.f;
    {
        const uint4* hp = (const uint4*)(g1 + (size_t)i*16);
        edge_acc(hp[0], hp[1], adv, M, acc, den);
    }
    walk8(ssrc, g1, beg, end, adv, M, acc, den);
    float inv = 1.0f/den;
    float an[14];
    #pragma unroll
    for (int f=0;f<14;f++) an[f] = acc[f]*inv;
    uint4* orow = (uint4*)(g2 + (size_t)i*32);
    #pragma unroll
    for (int g=0; g<4; g++){
        u32 ou[4];
        #pragma unroll
        for (int p=0;p<4;p++){
            int j0 = g*8 + 2*p;
            float va_ = b2s[j0], vb_ = b2s[j0+1];
            #pragma unroll
            for (int k=0;k<14;k++){ va_ += an[k]*W2s[k*32+j0]; vb_ += an[k]*W2s[k*32+j0+1]; }
            va_ = fmaxf(va_, 0.f); vb_ = fmaxf(vb_, 0.f);
            ou[p] = (u32)f2bf(va_) | ((u32)f2bf(vb_)<<16);
        }
        orow[g] = make_uint4(ou[0],ou[1],ou[2],ou[3]);
    }
}

// ---------------- pool (batch is sorted; binary search per graph) ----------------
__device__ __forceinline__ int lbound(const int* __restrict__ a, int n, int v){
    int lo=0, hi=n;
    while (lo < hi){ int m = (lo+hi)>>1; if (a[m] < v) lo = m+1; else hi = m; }
    return lo;
}

__global__ __launch_bounds__(64) void k_pool(const u16* __restrict__ g2, const int* __restrict__ batch,
        u16* __restrict__ comb, int N_){
    int b = blockIdx.x;
    int t = threadIdx.x, f = t & 31, half = t >> 5;
    int lo = lbound(batch, N_, b);
    int hi = lbound(batch, N_, b+1);
    float acc = 0.f;
    for (int i = lo + half; i < hi; i += 2) acc += bf2f(g2[(size_t)i*32 + f]);
    acc += __shfl_xor(acc, 32);
    if (t < 32) comb[(size_t)b*432 + f] = f2bf(acc);
}

// ---------------- standalone GEMM (fcc1) ----------------
__global__ __launch_bounds__(256) void k_gemm(const void* __restrict__ A, const u16* __restrict__ Wt,
        const void* __restrict__ bias, const void* __restrict__ bnp, void* __restrict__ out,
        int K, int Kp, int Nc, int ostride, int ooff, int do_relu,
        int out32, int araw, const int* __restrict__ flag){
    __shared__ u16 As[128][40];
    __shared__ u16 Bs[128][40];
    int is32 = *flag;
    gemm_block(As, Bs, A, Wt, bias, bnp, out, K, Kp, Nc, ostride, ooff, do_relu, out32,
               araw, is32, blockIdx.x*128, blockIdx.y*128, threadIdx.x);
}

// ---------------- final fcc2 (K=100, Nc=1) -> FP32 output ----------------
__global__ __launch_bounds__(256) void k_fcc2(const float* __restrict__ c1, const void* __restrict__ w,
        const void* __restrict__ b, float* __restrict__ outp, const int* __restrict__ flag){
    int is32 = *flag;
    __shared__ float wf[100];
    int t = threadIdx.x;
    if (t < 100) wf[t] = gload(w, t, is32);
    __syncthreads();
    int i = blockIdx.x*256 + t;
    const float* r = c1 + (size_t)i*100;
    float s = 0.f;
    #pragma unroll 4
    for (int k=0;k<100;k++) s += r[k]*wf[k];
    outp[i] = s + gload(b, 0, is32);
}

extern "C" void kernel_launch(void* const* d_in, const int* in_sizes, int n_in,
                              void* d_out, int out_size, void* d_ws, size_t ws_size,
                              hipStream_t stream){
    const int N = N_NODES, E = N_EDGES;
    const void* x    = d_in[0];
    const int* ei   = (const int*)d_in[1];
    const int* srcA = ei;
    const int* dstA = ei + E;
    const int* batch= (const int*)d_in[2];
    const void* fing = d_in[3];
    const void* tv   = d_in[4];
    const void* W1   = d_in[5];
    const void* as1w = d_in[6];
    const void* ad1w = d_in[7];
    const void* b1   = d_in[8];
    const void* W2   = d_in[9];
    const void* as2w = d_in[10];
    const void* ad2w = d_in[11];
    const void* b2   = d_in[12];
    const void* fc1w = d_in[13]; const void* fc1b = d_in[14]; const void* bn1 = d_in[15];
    const void* fc2w = d_in[16]; const void* fc2b = d_in[17]; const void* bn2 = d_in[18];
    const void* fc3w = d_in[19]; const void* fc3b = d_in[20]; const void* bn3 = d_in[21];
    const void* fc4w = d_in[22]; const void* fc4b = d_in[23]; const void* bn4 = d_in[24];
    const void* fccw = d_in[25]; const void* fccb = d_in[26]; const void* bnc = d_in[27];
    const void* fcc2w= d_in[28]; const void* fcc2b= d_in[29];

    char* ws = (char*)d_ws;
    size_t off = 0;
    auto alloc = [&](size_t bytes)->char*{ char* p = ws + off; off = (off + bytes + 255) & ~(size_t)255; return p; };
    int*  flagp  = (int*)alloc(256);          // [0]=dtype; [1]=gkey1; [2]=gkey2; +16B: prep[28]
    u32*  gkey1  = (u32*)flagp + 1;
    u32*  gkey2  = (u32*)flagp + 2;
    float* prep  = (float*)((char*)flagp + 16);
    int*  rowptr = (int*)alloc((size_t)(N+1)*4);
    int*  bsums  = (int*)alloc(513*4);
    u32*  tbl_bm = (u32*)alloc((size_t)BKTS*P_BLOCKS*4);
    u32*  tbl_km = (u32*)alloc(((size_t)BKTS*P_BLOCKS+1)*4);
    int*  ssrc   = (int*)alloc((size_t)E*4);       // 16 MB
    u16*  h1     = (u16*)alloc((size_t)N*16*2);    // 16.8 MB; comb aliases after g1mlp
    u16*  g1     = (u16*)alloc((size_t)N*16*2);    // 16.8 MB
    float* ad1_  = (float*)alloc((size_t)N*4);
    float* ad2_  = (float*)alloc((size_t)N*4);
    char* scr32  = alloc((size_t)N*32*2);          // 33.6 MB: btab -> g2
    float* c1    = (float*)alloc((size_t)N_GRAPH*100*4);
    u16*  Wt1    = (u16*)alloc((size_t)400*1024*2);
    u16*  Wt2    = (u16*)alloc((size_t)200*416*2);
    u16*  Wt3    = (u16*)alloc((size_t)400*256*2);
    u16*  Wt4    = (u16*)alloc((size_t)200*416*2);
    u16*  Wtc    = (u16*)alloc((size_t)100*448*2);
    u16*  fp1    = (u16*)alloc((size_t)N_GRAPH*400*2);   // 13.1 MB (written during g1mlp)
    u16*  tv1    = (u16*)alloc((size_t)N_GRAPH*400*2);   // 13.1 MB
    u32*  btab   = (u32*)scr32;                     // 16 MB during CSR build
    u16*  g2     = (u16*)scr32;                     // N*32 bf16 after gather2
    u16*  comb   = (u16*)h1;                        // 14.2 MB; h1 dead after g1mlp

    (void)hipMemsetAsync(flagp, 0, 256, stream);

    k_detect <<<1, 256, 0, stream>>>((const u32*)x, flagp, W2, as2w, ad2w, prep);

    // CSR p1 + weight transposes + linear1 in one launch
    k_p1t  <<<P_BLOCKS + TTOT + LBLK, 256, 0, stream>>>(dstA, tbl_bm,
                 fc1w, fc2w, fc3w, fc4w, fccw, Wt1, Wt2, Wt3, Wt4, Wtc, flagp,
                 x, W1, as1w, ad1w, h1, ad1_, gkey1);
    k_ttbl <<<dim3(32,16), 256, 0, stream>>>(tbl_bm, tbl_km);
    k_scan1<<<512,  256, 0, stream>>>((int*)tbl_km, bsums);
    k_scan2<<<1,    256, 0, stream>>>(bsums);
    k_scan3<<<(BKTS*P_BLOCKS)/256, 256, 0, stream>>>((int*)tbl_km, bsums, BKTS*P_BLOCKS, E);
    k_p2   <<<P_BLOCKS, 256, 0, stream>>>(srcA, dstA, tbl_km, btab);
    k_p3   <<<BKTS, 256, 0, stream>>>(tbl_km, btab, rowptr, ssrc);

    // gather1 (2048 blocks) + fc1/fc3 single-tile GEMMs (1024 blocks), 1:2, XCD-grouped
    k_g1mlp <<<3072, 256, 0, stream>>>(rowptr, ssrc, h1, ad1_, gkey1, b1, prep, g1, ad2_, gkey2, flagp,
                                       fing, Wt1, fc1b, bn1, fp1,
                                       tv,   Wt3, fc3b, bn3, tv1);
    // gather2 (2048 blocks) + fc2/fc4 single-tile GEMMs (512 blocks), 1:4, XCD-grouped
    k_g2mlp <<<2560, 256, 0, stream>>>(rowptr, ssrc, g1, ad2_, gkey2, W2, b2, g2, flagp,
                                       fp1, Wt2, fc2b, bn2,
                                       tv1, Wt4, fc4b, bn4, comb);
    k_pool   <<<N_GRAPH, 64, 0, stream>>>(g2, batch, comb, N);

    k_gemm<<<dim3(128,1), 256, 0, stream>>>(comb, Wtc, fccb, bnc, c1,  432, 448, 100, 100,   0, 1, 1, 0, flagp);

    k_fcc2<<<N_GRAPH/256, 256, 0, stream>>>(c1, fcc2w, fcc2b, (float*)d_out, flagp);
}